// Round 8
// baseline (199.723 us; speedup 1.0000x reference)
//
#include <hip/hip_runtime.h>

#define HW   262144   // 512*512
#define HW4  65536    // HW/4
#define NSEG 256
#define NB   8

typedef __attribute__((ext_vector_type(4))) float f32x4;
typedef __attribute__((ext_vector_type(8))) short s16x8;

__device__ __forceinline__ unsigned f2bf(float f) {   // fp32 -> bf16 (RNE)
  unsigned u = __float_as_uint(f);
  return (u + 0x7FFFu + ((u >> 16) & 1u)) >> 16;
}

// -------- Kernel 1: per-(batch,segment) moments via MFMA one-hot ----------
// R4-proven structure (44.7 us): [16][256] bf16 staging per wave, cheap
// tail (scatter to own region, 1 barrier, 4-region sum), 40 KB LDS ->
// 4 blocks/CU. Only addition vs R4: software prefetch of iteration 1's
// global loads (hides ~900-cyc HBM latency under iter 0's c-loop).
// Known 16-way conflict on the A-frag ds_read_b128 costs ~2 us total
// (measured R4: 2.1M conflict-cycles / 256 CU) -- accepted.
__global__ __launch_bounds__(256) void k_moments(const float* __restrict__ x,
                                                 const int* __restrict__ labels,
                                                 float* __restrict__ part) {
  __shared__ __align__(16) char smem[4][10240];  // per wave: mom 8KB + lab 1KB (bp aliases)
  const int t = threadIdx.x, w = t >> 6, lane = t & 63;
  const int b = blockIdx.x >> 7, blk = blockIdx.x & 127;  // 128 blocks/batch
  unsigned short* mom = (unsigned short*)smem[w];          // [16][256] bf16
  int* lab = (int*)(smem[w] + 8192);                       // [256]
  float* bp = (float*)smem[w];                             // [2560] aliases mom
  const int q = lane >> 4, n0 = lane & 15;

  // zero A rows 10..15 (keep unused D rows finite)
  #pragma unroll
  for (int m = 10; m < 16; ++m)
    *(uint2*)&mom[m * 256 + 4 * lane] = make_uint2(0u, 0u);

  const float4* __restrict__ x4 = (const float4*)(x + (size_t)b * 3 * HW);
  const int4*  __restrict__ l4  = (const int4*)(labels + (size_t)b * HW);

  f32x4 accv[16];
  #pragma unroll
  for (int i = 0; i < 16; ++i) accv[i] = (f32x4){0.f, 0.f, 0.f, 0.f};

  // prefetch iteration 0
  const int g0 = blk * 512 + w * 128 + lane;
  float4 na0 = x4[g0];
  float4 na1 = x4[HW4 + g0];
  float4 na2 = x4[2 * HW4 + g0];
  int4  nlb  = l4[g0];

  #pragma unroll
  for (int it = 0; it < 2; ++it) {
    float4 a0 = na0, a1 = na1, a2 = na2;
    int4 lb = nlb;
    if (it == 0) {             // prefetch iteration 1
      const int g1 = g0 + 64;
      na0 = x4[g1];
      na1 = x4[HW4 + g1];
      na2 = x4[2 * HW4 + g1];
      nlb = l4[g1];
    }

    float c0[4] = {a0.x, a0.y, a0.z, a0.w};
    float c1[4] = {a1.x, a1.y, a1.z, a1.w};
    float c2[4] = {a2.x, a2.y, a2.z, a2.w};
    float P[10][4];
    #pragma unroll
    for (int k = 0; k < 4; ++k) {
      P[0][k] = 1.f;
      P[1][k] = c0[k];          P[2][k] = c1[k];          P[3][k] = c2[k];
      P[4][k] = c0[k] * c0[k];  P[5][k] = c1[k] * c1[k];  P[6][k] = c2[k] * c2[k];
      P[7][k] = c0[k] * c1[k];  P[8][k] = c0[k] * c2[k];  P[9][k] = c1[k] * c2[k];
    }
    // stage transposed bf16 moments: mom[m][4*lane .. 4*lane+3]
    #pragma unroll
    for (int m = 0; m < 10; ++m) {
      unsigned lo = f2bf(P[m][0]) | (f2bf(P[m][1]) << 16);
      unsigned hi = f2bf(P[m][2]) | (f2bf(P[m][3]) << 16);
      *(uint2*)&mom[m * 256 + 4 * lane] = make_uint2(lo, hi);
    }
    *(int4*)&lab[4 * lane] = lb;
    // wave-private region + same-wave LDS ordering -> no barrier.

    #pragma unroll
    for (int c = 0; c < 8; ++c) {
      s16x8 af = *(s16x8*)&mom[n0 * 256 + c * 32 + q * 8];   // A[m=n0][k=q*8+j]
      int4 lA = *(int4*)&lab[c * 32 + q * 8];
      int4 lB = *(int4*)&lab[c * 32 + q * 8 + 4];
      int lv[8] = {lA.x, lA.y, lA.z, lA.w, lB.x, lB.y, lB.z, lB.w};
      unsigned mk[8];
      #pragma unroll
      for (int j = 0; j < 8; ++j) {
        int d = lv[j] - n0;
        unsigned hit = (((d & 15) == 0) && ((unsigned)d < 256u)) ? 1u : 0u;
        mk[j] = hit << (((unsigned)d >> 4) & 31u);
      }
      unsigned M01 = mk[0] | (mk[1] << 16);
      unsigned M23 = mk[2] | (mk[3] << 16);
      unsigned M45 = mk[4] | (mk[5] << 16);
      unsigned M67 = mk[6] | (mk[7] << 16);
      #pragma unroll
      for (int tl = 0; tl < 16; ++tl) {
        uint4 bi;
        bi.x = ((M01 >> tl) & 0x00010001u) * 0x3F80u;
        bi.y = ((M23 >> tl) & 0x00010001u) * 0x3F80u;
        bi.z = ((M45 >> tl) & 0x00010001u) * 0x3F80u;
        bi.w = ((M67 >> tl) & 0x00010001u) * 0x3F80u;
        s16x8 bf = __builtin_bit_cast(s16x8, bi);
        accv[tl] = __builtin_amdgcn_mfma_f32_16x16x32_bf16(af, bf, accv[tl], 0, 0, 0);
      }
    }
  }

  // cheap R4 tail: scatter D into own region, 1 barrier, 4-region sum
  #pragma unroll
  for (int tl = 0; tl < 16; ++tl)
    #pragma unroll
    for (int r = 0; r < 4; ++r) {
      const int m = q * 4 + r;
      if (m < 10) bp[m * 256 + tl * 16 + n0] = accv[tl][r];
    }
  __syncthreads();

  float* o = part + (size_t)blockIdx.x * 2560;
  for (int i = t; i < 2560; i += 256) {
    float s = ((float*)smem[0])[i] + ((float*)smem[1])[i]
            + ((float*)smem[2])[i] + ((float*)smem[3])[i];
    o[i] = s;
  }
}

// -------- Kernel 2: fused reduce->stats->reduce_conv->normalize->sim ------
// One block per 64x64 sim tile (128 blocks). Phase A: sum this batch's 128
// k_moments partials into LDS (1.31 MB/block, independent coalesced loads).
// Phase B: recompute normalized features for the tile's 128 segments
// (dot split into 4 chains to break the serial-FMA dependence). Phase C:
// fp32 tile GEMM + conv/BN/ReLU epilogue.
__global__ __launch_bounds__(256) void k_statsim(const float* __restrict__ part,
                                                 const float* __restrict__ W_pix,
                                                 const float* __restrict__ b_pix,
                                                 const float* __restrict__ W_red,
                                                 const float* __restrict__ b_red,
                                                 float* __restrict__ out,
                                                 const float* __restrict__ w_sim,
                                                 const float* __restrict__ b_sim,
                                                 const float* __restrict__ bn_g,
                                                 const float* __restrict__ bn_b,
                                                 const float* __restrict__ bn_m,
                                                 const float* __restrict__ bn_v) {
  __shared__ float accs[2560];
  __shared__ float wred[64 * 129];
  __shared__ float comb[4][132];
  __shared__ float rnA[64 * 65];
  __shared__ float rnB[64 * 65];
  const int t  = threadIdx.x;
  const int b  = blockIdx.x >> 4;
  const int ti = (blockIdx.x >> 2) & 3;
  const int tj = blockIdx.x & 3;

  // Phase A: cross-block reduce of this batch's partials
  {
    const float* p0 = part + (size_t)(b * 128) * 2560;
    for (int e = t; e < 2560; e += 256) {
      const float* p = p0 + e;
      float s0 = 0.f, s1 = 0.f, s2 = 0.f, s3 = 0.f;
      for (int j = 0; j < 128; j += 4) {
        s0 += p[(size_t)(j + 0) * 2560];
        s1 += p[(size_t)(j + 1) * 2560];
        s2 += p[(size_t)(j + 2) * 2560];
        s3 += p[(size_t)(j + 3) * 2560];
      }
      accs[e] = (s0 + s1) + (s2 + s3);
    }
  }
  // stage W_red (64x128) padded stride 129
  for (int j4 = t; j4 < 2048; j4 += 256) {
    const int row = j4 >> 5, c4 = (j4 & 31) << 2;
    float4 v = ((const float4*)W_red)[j4];
    float* d = &wred[row * 129 + c4];
    d[0] = v.x; d[1] = v.y; d[2] = v.z; d[3] = v.w;
  }
  __syncthreads();

  // Phase B: stats -> reduce_conv -> L2 normalize for row/col segments
  const int w = t >> 6, f = t & 63;
  const float w0 = W_pix[f * 3 + 0];
  const float w1 = W_pix[f * 3 + 1];
  const float w2 = W_pix[f * 3 + 2];
  const float bfp = b_pix[f];
  const float br  = b_red[f];

  #pragma unroll
  for (int half = 0; half < 2; ++half) {
    const int tt = half ? tj : ti;
    float* rnT = half ? rnB : rnA;
    for (int ii = w; ii < 64; ii += 4) {
      const int s = tt * 64 + ii;
      const float N   = fmaxf(accs[0 * 256 + s], 1.f);
      const float S0  = accs[1 * 256 + s];
      const float S1  = accs[2 * 256 + s];
      const float S2  = accs[3 * 256 + s];
      const float M00 = accs[4 * 256 + s];
      const float M11 = accs[5 * 256 + s];
      const float M22 = accs[6 * 256 + s];
      const float M01 = accs[7 * 256 + s];
      const float M02 = accs[8 * 256 + s];
      const float M12 = accs[9 * 256 + s];

      const float wS   = w0 * S0 + w1 * S1 + w2 * S2;
      const float mean = (wS + N * bfp) / N;
      const float ssq  = w0 * w0 * M00 + w1 * w1 * M11 + w2 * w2 * M22
                       + 2.f * (w0 * w1 * M01 + w0 * w2 * M02 + w1 * w2 * M12)
                       + 2.f * bfp * wS + N * bfp * bfp;
      const float var  = ssq / N - mean * mean;
      const float stdv = sqrtf(fmaxf(var, 1e-6f));

      comb[w][f]      = mean;     // per-wave buffer, same-wave LDS ordering
      comb[w][64 + f] = stdv;

      const float* wr = &wred[f * 129];
      const float* cb = comb[w];
      float r0 = br, r1 = 0.f, r2 = 0.f, r3 = 0.f;
      for (int g = 0; g < 128; g += 4) {   // 4 chains: break serial FMA dep
        r0 += wr[g + 0] * cb[g + 0];
        r1 += wr[g + 1] * cb[g + 1];
        r2 += wr[g + 2] * cb[g + 2];
        r3 += wr[g + 3] * cb[g + 3];
      }
      const float r = (r0 + r1) + (r2 + r3);

      float sq = r * r;
      #pragma unroll
      for (int off = 32; off > 0; off >>= 1) sq += __shfl_xor(sq, off, 64);
      rnT[ii * 65 + f] = r / fmaxf(sqrtf(sq), 1e-12f);
    }
  }
  __syncthreads();

  // Phase C: 64x64 tile GEMM + fused conv1x1 + BN(eval) + ReLU
  const int tx = t & 15;
  const int ty = t >> 4;
  float accd[4][4] = {{0.f}};
  for (int k = 0; k < 64; ++k) {
    float av[4], bv[4];
    #pragma unroll
    for (int i = 0; i < 4; ++i) av[i] = rnA[(ty * 4 + i) * 65 + k];
    #pragma unroll
    for (int j = 0; j < 4; ++j) bv[j] = rnB[(tx * 4 + j) * 65 + k];
    #pragma unroll
    for (int i = 0; i < 4; ++i)
      #pragma unroll
      for (int j = 0; j < 4; ++j) accd[i][j] += av[i] * bv[j];
  }

  const float invsd = 1.0f / sqrtf(bn_v[0] + 1e-5f);
  const float scale = w_sim[0] * bn_g[0] * invsd;
  const float shift = (b_sim[0] - bn_m[0]) * bn_g[0] * invsd + bn_b[0];

  #pragma unroll
  for (int i = 0; i < 4; ++i) {
    float4 v;
    v.x = fmaxf(accd[i][0] * scale + shift, 0.f);
    v.y = fmaxf(accd[i][1] * scale + shift, 0.f);
    v.z = fmaxf(accd[i][2] * scale + shift, 0.f);
    v.w = fmaxf(accd[i][3] * scale + shift, 0.f);
    const int base = b * 65536 + (ti * 64 + ty * 4 + i) * 256 + tj * 64;
    ((float4*)out)[(base >> 2) + tx] = v;
  }
}

extern "C" void kernel_launch(void* const* d_in, const int* in_sizes, int n_in,
                              void* d_out, int out_size, void* d_ws, size_t ws_size,
                              hipStream_t stream) {
  (void)in_sizes; (void)n_in; (void)out_size; (void)ws_size;
  const float* x      = (const float*)d_in[0];
  const int*   labels = (const int*)d_in[1];
  const float* W_pix  = (const float*)d_in[3];
  const float* b_pix  = (const float*)d_in[4];
  const float* W_red  = (const float*)d_in[5];
  const float* b_red  = (const float*)d_in[6];
  const float* w_sim  = (const float*)d_in[7];
  const float* b_sim  = (const float*)d_in[8];
  const float* bn_g   = (const float*)d_in[9];
  const float* bn_b   = (const float*)d_in[10];
  const float* bn_m   = (const float*)d_in[11];
  const float* bn_v   = (const float*)d_in[12];
  float* out = (float*)d_out;

  float* part = (float*)d_ws;        // 1024*2560 f32 = 10.5 MB

  k_moments<<<dim3(1024), dim3(256), 0, stream>>>(x, labels, part);
  k_statsim<<<dim3(128), dim3(256), 0, stream>>>(part, W_pix, b_pix, W_red, b_red,
                                                 out, w_sim, b_sim, bn_g, bn_b,
                                                 bn_m, bn_v);
}

// Round 9
// 157.148 us; speedup vs baseline: 1.2709x; 1.2709x over previous
//
#include <hip/hip_runtime.h>

#define HW   262144   // 512*512
#define HW4  65536    // HW/4
#define NSEG 256
#define NB   8

typedef __attribute__((ext_vector_type(4))) float f32x4;
typedef __attribute__((ext_vector_type(8))) short s16x8;

__device__ __forceinline__ unsigned f2bf(float f) {   // fp32 -> bf16 (RNE)
  unsigned u = __float_as_uint(f);
  return (u + 0x7FFFu + ((u >> 16) & 1u)) >> 16;
}

// -------- Kernel 1: per-(batch,segment) moments via MFMA one-hot ----------
// R4-proven structure + prefetch (R8-verified: dropped out of top-5).
// [16][256] bf16 staging per wave, cheap tail (scatter to own region,
// 1 barrier, 4-region sum), 40 KB LDS -> 4 blocks/CU.
__global__ __launch_bounds__(256) void k_moments(const float* __restrict__ x,
                                                 const int* __restrict__ labels,
                                                 float* __restrict__ part) {
  __shared__ __align__(16) char smem[4][10240];  // per wave: mom 8KB + lab 1KB (bp aliases)
  const int t = threadIdx.x, w = t >> 6, lane = t & 63;
  const int b = blockIdx.x >> 7, blk = blockIdx.x & 127;  // 128 blocks/batch
  unsigned short* mom = (unsigned short*)smem[w];          // [16][256] bf16
  int* lab = (int*)(smem[w] + 8192);                       // [256]
  float* bp = (float*)smem[w];                             // [2560] aliases mom
  const int q = lane >> 4, n0 = lane & 15;

  // zero A rows 10..15 (keep unused D rows finite)
  #pragma unroll
  for (int m = 10; m < 16; ++m)
    *(uint2*)&mom[m * 256 + 4 * lane] = make_uint2(0u, 0u);

  const float4* __restrict__ x4 = (const float4*)(x + (size_t)b * 3 * HW);
  const int4*  __restrict__ l4  = (const int4*)(labels + (size_t)b * HW);

  f32x4 accv[16];
  #pragma unroll
  for (int i = 0; i < 16; ++i) accv[i] = (f32x4){0.f, 0.f, 0.f, 0.f};

  // prefetch iteration 0
  const int g0 = blk * 512 + w * 128 + lane;
  float4 na0 = x4[g0];
  float4 na1 = x4[HW4 + g0];
  float4 na2 = x4[2 * HW4 + g0];
  int4  nlb  = l4[g0];

  #pragma unroll
  for (int it = 0; it < 2; ++it) {
    float4 a0 = na0, a1 = na1, a2 = na2;
    int4 lb = nlb;
    if (it == 0) {             // prefetch iteration 1
      const int g1 = g0 + 64;
      na0 = x4[g1];
      na1 = x4[HW4 + g1];
      na2 = x4[2 * HW4 + g1];
      nlb = l4[g1];
    }

    float c0[4] = {a0.x, a0.y, a0.z, a0.w};
    float c1[4] = {a1.x, a1.y, a1.z, a1.w};
    float c2[4] = {a2.x, a2.y, a2.z, a2.w};
    float P[10][4];
    #pragma unroll
    for (int k = 0; k < 4; ++k) {
      P[0][k] = 1.f;
      P[1][k] = c0[k];          P[2][k] = c1[k];          P[3][k] = c2[k];
      P[4][k] = c0[k] * c0[k];  P[5][k] = c1[k] * c1[k];  P[6][k] = c2[k] * c2[k];
      P[7][k] = c0[k] * c1[k];  P[8][k] = c0[k] * c2[k];  P[9][k] = c1[k] * c2[k];
    }
    // stage transposed bf16 moments: mom[m][4*lane .. 4*lane+3]
    #pragma unroll
    for (int m = 0; m < 10; ++m) {
      unsigned lo = f2bf(P[m][0]) | (f2bf(P[m][1]) << 16);
      unsigned hi = f2bf(P[m][2]) | (f2bf(P[m][3]) << 16);
      *(uint2*)&mom[m * 256 + 4 * lane] = make_uint2(lo, hi);
    }
    *(int4*)&lab[4 * lane] = lb;
    // wave-private region + same-wave LDS ordering -> no barrier.

    #pragma unroll
    for (int c = 0; c < 8; ++c) {
      s16x8 af = *(s16x8*)&mom[n0 * 256 + c * 32 + q * 8];   // A[m=n0][k=q*8+j]
      int4 lA = *(int4*)&lab[c * 32 + q * 8];
      int4 lB = *(int4*)&lab[c * 32 + q * 8 + 4];
      int lv[8] = {lA.x, lA.y, lA.z, lA.w, lB.x, lB.y, lB.z, lB.w};
      unsigned mk[8];
      #pragma unroll
      for (int j = 0; j < 8; ++j) {
        int d = lv[j] - n0;
        unsigned hit = (((d & 15) == 0) && ((unsigned)d < 256u)) ? 1u : 0u;
        mk[j] = hit << (((unsigned)d >> 4) & 31u);
      }
      unsigned M01 = mk[0] | (mk[1] << 16);
      unsigned M23 = mk[2] | (mk[3] << 16);
      unsigned M45 = mk[4] | (mk[5] << 16);
      unsigned M67 = mk[6] | (mk[7] << 16);
      #pragma unroll
      for (int tl = 0; tl < 16; ++tl) {
        uint4 bi;
        bi.x = ((M01 >> tl) & 0x00010001u) * 0x3F80u;
        bi.y = ((M23 >> tl) & 0x00010001u) * 0x3F80u;
        bi.z = ((M45 >> tl) & 0x00010001u) * 0x3F80u;
        bi.w = ((M67 >> tl) & 0x00010001u) * 0x3F80u;
        s16x8 bf = __builtin_bit_cast(s16x8, bi);
        accv[tl] = __builtin_amdgcn_mfma_f32_16x16x32_bf16(af, bf, accv[tl], 0, 0, 0);
      }
    }
  }

  // cheap R4 tail: scatter D into own region, 1 barrier, 4-region sum
  #pragma unroll
  for (int tl = 0; tl < 16; ++tl)
    #pragma unroll
    for (int r = 0; r < 4; ++r) {
      const int m = q * 4 + r;
      if (m < 10) bp[m * 256 + tl * 16 + n0] = accv[tl][r];
    }
  __syncthreads();

  float* o = part + (size_t)blockIdx.x * 2560;
  for (int i = t; i < 2560; i += 256) {
    float s = ((float*)smem[0])[i] + ((float*)smem[1])[i]
            + ((float*)smem[2])[i] + ((float*)smem[3])[i];
    o[i] = s;
  }
}

// -------- Kernel 2: fused gather-reduce -> stats -> conv -> normalize -----
// 512 blocks, one segment per wave (2048 waves). Each wave gathers its
// segment's 10 moments from the 128 block-partials (20 independent scattered
// loads/lane), butterfly-reduces across 64 lanes -> every lane holds all 10
// sums in registers. Then the R4-proven stats/dot/normalize path.
__global__ __launch_bounds__(256) void k_statsn(const float* __restrict__ part,
                                                const float* __restrict__ W_pix,
                                                const float* __restrict__ b_pix,
                                                const float* __restrict__ W_red,
                                                const float* __restrict__ b_red,
                                                float* __restrict__ rn) {
  __shared__ float wred[64 * 129];   // +1 pad, conflict-free
  __shared__ float comb[4][132];
  const int t = threadIdx.x;

  // stage W_red (64x128) coalesced, padded stride 129
  for (int j4 = t; j4 < 2048; j4 += 256) {
    const int row = j4 >> 5, c4 = (j4 & 31) << 2;
    float4 v = ((const float4*)W_red)[j4];
    float* d = &wred[row * 129 + c4];
    d[0] = v.x; d[1] = v.y; d[2] = v.z; d[3] = v.w;
  }
  __syncthreads();

  const int w = t >> 6, f = t & 63;
  const int seg = blockIdx.x * 4 + w;   // 0..2047
  const int b = seg >> 8;
  const int s = seg & 255;

  // gather-reduce: partial rows b*128 .. b*128+127, element m*256+s
  const float* p = part + (size_t)(b * 128) * 2560 + s;
  float mv[10];
  #pragma unroll
  for (int m = 0; m < 10; ++m) {
    const float* pm = p + m * 256;
    float v = pm[(size_t)f * 2560] + pm[(size_t)(64 + f) * 2560];
    #pragma unroll
    for (int off = 32; off > 0; off >>= 1) v += __shfl_xor(v, off, 64);
    mv[m] = v;   // all lanes hold the total after butterfly
  }

  const float N   = fmaxf(mv[0], 1.0f);
  const float S0  = mv[1], S1 = mv[2], S2 = mv[3];
  const float M00 = mv[4], M11 = mv[5], M22 = mv[6];
  const float M01 = mv[7], M02 = mv[8], M12 = mv[9];

  const float w0 = W_pix[f * 3 + 0];
  const float w1 = W_pix[f * 3 + 1];
  const float w2 = W_pix[f * 3 + 2];
  const float bf = b_pix[f];

  const float wS   = w0 * S0 + w1 * S1 + w2 * S2;
  const float mean = (wS + N * bf) / N;
  const float ssq  = w0 * w0 * M00 + w1 * w1 * M11 + w2 * w2 * M22
                   + 2.f * (w0 * w1 * M01 + w0 * w2 * M02 + w1 * w2 * M12)
                   + 2.f * bf * wS + N * bf * bf;
  const float var  = ssq / N - mean * mean;
  const float stdv = sqrtf(fmaxf(var, 1e-6f));

  comb[w][f]      = mean;     // per-wave buffer; same-wave LDS ordering
  comb[w][64 + f] = stdv;

  const float* wr = &wred[f * 129];
  const float* cb = comb[w];
  float r0 = b_red[f], r1 = 0.f, r2 = 0.f, r3 = 0.f;
  for (int g = 0; g < 128; g += 4) {   // 4 chains break serial FMA dep
    r0 += wr[g + 0] * cb[g + 0];
    r1 += wr[g + 1] * cb[g + 1];
    r2 += wr[g + 2] * cb[g + 2];
    r3 += wr[g + 3] * cb[g + 3];
  }
  const float r = (r0 + r1) + (r2 + r3);

  float sq = r * r;
  #pragma unroll
  for (int off = 32; off > 0; off >>= 1) sq += __shfl_xor(sq, off, 64);
  const float inv = 1.0f / fmaxf(sqrtf(sq), 1e-12f);

  rn[(size_t)seg * 64 + f] = r * inv;
}

// -------- Kernel 3: sim = rn rn^T, fused conv1x1 + BN(eval) + ReLU --------
__global__ __launch_bounds__(256) void k_sim(const float* __restrict__ rn,
                                             float* __restrict__ out,
                                             const float* __restrict__ w_sim,
                                             const float* __restrict__ b_sim,
                                             const float* __restrict__ bn_g,
                                             const float* __restrict__ bn_b,
                                             const float* __restrict__ bn_m,
                                             const float* __restrict__ bn_v) {
  __shared__ float A[64 * 65];
  __shared__ float Bt[64 * 65];
  const int t  = threadIdx.x;
  const int b  = blockIdx.x >> 4;
  const int ti = (blockIdx.x >> 2) & 3;
  const int tj = blockIdx.x & 3;

  const float4* rn4 = (const float4*)(rn + (size_t)b * NSEG * 64);
  for (int j4 = t; j4 < 1024; j4 += 256) {
    const int row = j4 >> 4;
    const int c4  = (j4 & 15) << 2;
    float4 va = rn4[(ti * 64 + row) * 16 + (j4 & 15)];
    float* da = &A[row * 65 + c4];
    da[0] = va.x; da[1] = va.y; da[2] = va.z; da[3] = va.w;
    float4 vb = rn4[(tj * 64 + row) * 16 + (j4 & 15)];
    float* db = &Bt[row * 65 + c4];
    db[0] = vb.x; db[1] = vb.y; db[2] = vb.z; db[3] = vb.w;
  }
  __syncthreads();

  const int tx = t & 15;
  const int ty = t >> 4;
  float acc[4][4] = {{0.f}};
  for (int k = 0; k < 64; ++k) {
    float av[4], bv[4];
    #pragma unroll
    for (int i = 0; i < 4; ++i) av[i] = A[(ty * 4 + i) * 65 + k];
    #pragma unroll
    for (int j = 0; j < 4; ++j) bv[j] = Bt[(tx * 4 + j) * 65 + k];
    #pragma unroll
    for (int i = 0; i < 4; ++i)
      #pragma unroll
      for (int j = 0; j < 4; ++j) acc[i][j] += av[i] * bv[j];
  }

  const float invsd = 1.0f / sqrtf(bn_v[0] + 1e-5f);
  const float scale = w_sim[0] * bn_g[0] * invsd;
  const float shift = (b_sim[0] - bn_m[0]) * bn_g[0] * invsd + bn_b[0];

  #pragma unroll
  for (int i = 0; i < 4; ++i) {
    float4 v;
    v.x = fmaxf(acc[i][0] * scale + shift, 0.f);
    v.y = fmaxf(acc[i][1] * scale + shift, 0.f);
    v.z = fmaxf(acc[i][2] * scale + shift, 0.f);
    v.w = fmaxf(acc[i][3] * scale + shift, 0.f);
    const int base = b * 65536 + (ti * 64 + ty * 4 + i) * 256 + tj * 64;
    ((float4*)out)[(base >> 2) + tx] = v;
  }
}

extern "C" void kernel_launch(void* const* d_in, const int* in_sizes, int n_in,
                              void* d_out, int out_size, void* d_ws, size_t ws_size,
                              hipStream_t stream) {
  (void)in_sizes; (void)n_in; (void)out_size; (void)ws_size;
  const float* x      = (const float*)d_in[0];
  const int*   labels = (const int*)d_in[1];
  const float* W_pix  = (const float*)d_in[3];
  const float* b_pix  = (const float*)d_in[4];
  const float* W_red  = (const float*)d_in[5];
  const float* b_red  = (const float*)d_in[6];
  const float* w_sim  = (const float*)d_in[7];
  const float* b_sim  = (const float*)d_in[8];
  const float* bn_g   = (const float*)d_in[9];
  const float* bn_b   = (const float*)d_in[10];
  const float* bn_m   = (const float*)d_in[11];
  const float* bn_v   = (const float*)d_in[12];
  float* out = (float*)d_out;

  float* part = (float*)d_ws;                     // 1024*2560 f32 = 10.5 MB
  float* rn   = part + (size_t)1024 * 2560;       // 8*256*64 f32 = 512 KB

  k_moments<<<dim3(1024), dim3(256), 0, stream>>>(x, labels, part);
  k_statsn<<<dim3(512), dim3(256), 0, stream>>>(part, W_pix, b_pix, W_red, b_red, rn);
  k_sim<<<dim3(128), dim3(256), 0, stream>>>(rn, out, w_sim, b_sim, bn_g, bn_b, bn_m, bn_v);
}